// Round 9
// baseline (219.025 us; speedup 1.0000x reference)
//
#include <hip/hip_runtime.h>
#include <hip/hip_cooperative_groups.h>
#include <hip/hip_bf16.h>
#include <cmath>

namespace cg = cooperative_groups;

constexpr int KN   = 8;     // spline knots
constexpr int NPAR = 23;    // 3K-1
constexpr int DD   = 32;    // DIM
constexpr float BND   = 3.0f;
constexpr float MINBW = 1e-3f;
constexpr float MIND  = 1e-3f;

#define TPB   256
#define ROWS  256    // batch rows per block
#define GDIMS 8      // output dims per block (4 groups cover 32)
#define NGRP  (DD / GDIMS)
#define WST   40     // packed W row stride (shorts): 80B, 16B-aligned
#define PSTH  24     // sP row stride (halves): 48B, 16B-aligned, conflict-free
#define ZST   12     // sZ row stride (floats): 48B, 16B-aligned
#define RECB  8192   // per-layer packed weight record bytes

typedef __attribute__((ext_vector_type(8))) short short8;      // 8 bf16 (MFMA A/B frag)
typedef __attribute__((ext_vector_type(4))) float float4v;     // MFMA C/D frag
typedef __attribute__((ext_vector_type(2))) __fp16 fp16x2;     // cvt_pkrtz result type
typedef __attribute__((ext_vector_type(8))) _Float16 half8v;

#define RCP(x) __builtin_amdgcn_rcpf(x)

__device__ __forceinline__ short f2bf(float f) {
    unsigned u = __float_as_uint(f);
    u += 0x7fffu + ((u >> 16) & 1u);     // round-to-nearest-even
    return (short)(u >> 16);
}

__device__ __forceinline__ int pkbf(float a, float b) {
    union { __hip_bfloat162 v; int i; } u;
    u.v = __float22bfloat162_rn(make_float2(a, b));
    return u.i;
}

// packed f32x2 -> f16x2 as raw int
__device__ __forceinline__ int pkh(float a, float b) {
    union { fp16x2 h; int i; } u;
    u.h = __builtin_amdgcn_cvt_pkrtz(a, b);
    return u.i;
}

// tanh = 1 - 2/(e^2x + 1): exact at both tails
__device__ __forceinline__ float fast_tanh(float x) {
    float e = __expf(2.0f * x);
    return 1.0f - 2.0f * RCP(e + 1.0f);
}

// softplus for |v| <= ~8: e^v can't overflow
__device__ __forceinline__ float softplus_fast(float v) {
    return __logf(1.0f + __expf(v));
}

// Rational-quadratic spline. p[0:8]=W logits, p[8:16]=H logits, p[16:23]=D
// logits. Derivative gather: only the 2 needed D-logits are selected in the
// bin-search chain and double-softplus'd (edges pinned to exactly 1.0).
__device__ __forceinline__ float rqs_apply(float xv, const float* p, float& ldout) {
    float cw[KN + 1], ch[KN + 1];
    {
        float t0[KN]; float s = 0.f;
#pragma unroll
        for (int k = 0; k < KN; ++k) { t0[k] = __expf(p[k]); s += t0[k]; }
        float inv = (2.0f * BND) * RCP(s);
        float e2[KN]; float s2 = 0.f;
#pragma unroll
        for (int k = 0; k < KN; ++k) { e2[k] = __expf(inv * t0[k]); s2 += e2[k]; }
        float fac = (1.0f - MINBW * KN) * RCP(s2);
        float c = 0.f;
        cw[0] = -BND;
#pragma unroll
        for (int k = 0; k < KN; ++k) { c += MINBW + fac * e2[k]; cw[k + 1] = 2.0f * BND * c - BND; }
        cw[KN] = BND;
    }
    {
        float t0[KN]; float s = 0.f;
#pragma unroll
        for (int k = 0; k < KN; ++k) { t0[k] = __expf(p[KN + k]); s += t0[k]; }
        float inv = (2.0f * BND) * RCP(s);
        float e2[KN]; float s2 = 0.f;
#pragma unroll
        for (int k = 0; k < KN; ++k) { e2[k] = __expf(inv * t0[k]); s2 += e2[k]; }
        float fac = (1.0f - MINBW * KN) * RCP(s2);
        float c = 0.f;
        ch[0] = -BND;
#pragma unroll
        for (int k = 0; k < KN; ++k) { c += MINBW + fac * e2[k]; ch[k + 1] = 2.0f * BND * c - BND; }
        ch[KN] = BND;
    }

    float xc = fminf(fmaxf(xv, -BND), BND);
    float in_cw = cw[0], in_w = cw[1] - cw[0];
    float in_ch = ch[0], in_h = ch[1] - ch[0];
    float dl0 = 0.0f, dl1 = p[2 * KN];
    bool e0 = true, e1 = false;
#pragma unroll
    for (int k = 1; k < KN; ++k) {
        bool c = (xc >= cw[k]);
        in_cw = c ? cw[k]            : in_cw;
        in_w  = c ? (cw[k+1]-cw[k])  : in_w;
        in_ch = c ? ch[k]            : in_ch;
        in_h  = c ? (ch[k+1]-ch[k])  : in_h;
        dl0   = c ? p[2*KN + k - 1]  : dl0;
        if (k < KN - 1) dl1 = c ? p[2*KN + k] : dl1;
        if (k == 1)      e0 = !c;
        if (k == KN - 1) e1 = c;
    }
    float d0 = e0 ? 1.0f : (MIND + softplus_fast(softplus_fast(dl0)));
    float d1 = e1 ? 1.0f : (MIND + softplus_fast(softplus_fast(dl1)));

    float rw    = RCP(in_w);
    float th    = (xc - in_cw) * rw;
    float delta = in_h * rw;
    float tt    = th * (1.0f - th);
    float th2   = th * th;
    float num   = in_h * (delta * th2 + d0 * tt);
    float den   = delta + (d0 + d1 - 2.0f * delta) * tt;
    float z     = in_ch + num * RCP(den);
    float omt   = 1.0f - th;
    float dnum  = delta * delta * (d1 * th2 + 2.0f * delta * tt + d0 * omt * omt);
    float ldv   = __logf(dnum) - 2.0f * __logf(den);

    bool inside = (xv >= -BND) && (xv <= BND);
    ldout = inside ? ldv : 0.0f;
    return inside ? z : xv;
}

// C-layout -> B-frag cross-lane transpose (register-only, verified R6)
__device__ __forceinline__ short8 xpose_h(float4v cA, float4v cB,
                                          float4 bA, float4 bB,
                                          int odd, int sl_a, int sl_b, bool qlow) {
    int a0 = pkbf(fast_tanh(cA[0] + bA.x), fast_tanh(cA[1] + bA.y));
    int a1 = pkbf(fast_tanh(cA[2] + bA.z), fast_tanh(cA[3] + bA.w));
    int b0 = pkbf(fast_tanh(cB[0] + bB.x), fast_tanh(cB[1] + bB.y));
    int b1 = pkbf(fast_tanh(cB[2] + bB.z), fast_tanh(cB[3] + bB.w));
    int p0 = odd ? b0 : a0, p1 = odd ? b1 : a1;
    int p2 = odd ? a0 : b0, p3 = odd ? a1 : b1;
    int g0 = __shfl(p0, sl_a, 64);
    int g1 = __shfl(p1, sl_a, 64);
    int g2 = __shfl(p2, sl_b, 64);
    int g3 = __shfl(p3, sl_b, 64);
    union { int4 i; short8 s; } u;
    u.i = qlow ? make_int4(g0, g1, g2, g3) : make_int4(g2, g3, g0, g1);
    return u.s;
}

// ---- record packing (device helper; per-layer l) ----
__device__ __forceinline__ void pack_record(int l, int tid,
       const float* __restrict__ w1, const float* __restrict__ b1,
       const float* __restrict__ w2, const float* __restrict__ b2,
       const float* __restrict__ w3, const float* __restrict__ b3,
       char* __restrict__ wbuf)
{
    short* r1 = (short*)(wbuf + (size_t)l * RECB);
    short* r2 = r1 + 1280;
    short* r3 = r2 + 1280;
    float* f1 = (float*)(wbuf + (size_t)l * RECB + 7680);
    float* f2 = f1 + 32;
    float* f3 = f2 + 32;
    const float* g1 = w1 + (size_t)l * 992;    // [31][32]
    const float* g2 = w2 + (size_t)l * 1024;   // [32][32]
    const float* g3 = w3 + (size_t)l * 736;    // [32][23]
    for (int i = tid; i < 1280; i += 256) {
        int n = i / WST, k = i - WST * n;
        r1[i] = (k < 31) ? f2bf(g1[k * 32 + n]) : (short)0;
        r2[i] = (k < 32) ? f2bf(g2[k * 32 + n]) : (short)0;
        r3[i] = (n < 23 && k < 32) ? f2bf(g3[k * 23 + n]) : (short)0;
    }
    if (tid < 32) { f1[tid] = b1[(size_t)l * 32 + tid]; f2[tid] = b2[(size_t)l * 32 + tid]; }
    if (tid < 32) f3[tid] = (tid < 23) ? b3[(size_t)l * 23 + tid] : 0.0f;
}

__device__ __forceinline__ void zero_chunk(int zb, int tid, float* ldo, int B) {
    const int chunk = B >> 6;
    float4* dst = (float4*)(ldo + (size_t)zb * chunk);
    for (int i = tid; i < (chunk >> 2); i += 256)
        dst[i] = make_float4(0.f, 0.f, 0.f, 0.f);
}

// ---- main per-block body: 256 rows x 8 output dims (rolled layer loop) ----
__device__ __forceinline__ void nsf_body(
      const float* __restrict__ x, const float* __restrict__ p0,
      const char* __restrict__ wbuf,
      float* __restrict__ zo, float* __restrict__ ldo, int B,
      char* sRec, _Float16* sP, float* sZ)
{
    const short* sW1 = (const short*)sRec;
    const short* sW2 = sW1 + 1280;
    const short* sW3 = sW1 + 2560;
    const float* sB1 = (const float*)(sRec + 7680);
    const float* sB2 = sB1 + 32;
    const float* sB3 = sB1 + 64;

    const int tid  = threadIdx.x;
    const int lane = tid & 63;
    const int wv   = tid >> 6;
    const int q    = lane >> 4;
    const int ln   = lane & 15;
    const int qb   = q & 1;
    const bool qlow = (q < 2);
    const int s_even = ln + 32 * qb;
    const int s_odd  = s_even + 16;
    const int sl_a = qlow ? s_even : s_odd;
    const int sl_b = qlow ? s_odd  : s_even;
    const int g    = blockIdx.y;
    const int ly0  = GDIMS * g;
    const long long rowbase = (long long)blockIdx.x * ROWS;
    const long long row = rowbase + tid;

    // spline inputs -> sZ slots (overwritten with z after each spline)
    {
        const float4* xp = (const float4*)(x + row * DD + ly0);
        *(float4*)&sZ[tid * ZST]     = xp[0];
        *(float4*)&sZ[tid * ZST + 4] = xp[1];
    }
    float ldacc = 0.0f;

    for (int j = 0; j < GDIMS; ++j) {
        const int ly = ly0 + j;
        float xv = sZ[tid * ZST + j];
        float z, ld;
        if (ly == 0) {
            float pr[NPAR];
#pragma unroll
            for (int k = 0; k < NPAR; ++k) pr[k] = p0[k];
            z = rqs_apply(xv, pr, ld);
        } else {
            const int l = ly - 1;
            __syncthreads();   // protect sRec/sP from previous layer
            {
                const int4* src = (const int4*)(wbuf + (size_t)l * RECB);
                int4* dst = (int4*)sRec;
                dst[tid]       = src[tid];
                dst[tid + 256] = src[tid + 256];
            }
            __syncthreads();

            short8 w1a = *(const short8*)&sW1[ln * WST + q * 8];
            short8 w1b = *(const short8*)&sW1[(16 + ln) * WST + q * 8];
            short8 w2a = *(const short8*)&sW2[ln * WST + q * 8];
            short8 w2b = *(const short8*)&sW2[(16 + ln) * WST + q * 8];
            short8 w3a = *(const short8*)&sW3[ln * WST + q * 8];
            short8 w3b = *(const short8*)&sW3[(16 + ln) * WST + q * 8];
            float4 bA1 = *(const float4*)&sB1[4 * q];
            float4 bB1 = *(const float4*)&sB1[16 + 4 * q];
            float4 bA2 = *(const float4*)&sB2[4 * q];
            float4 bB2 = *(const float4*)&sB2[16 + 4 * q];
            float4 bA3 = *(const float4*)&sB3[4 * q];
            float4 bB3 = *(const float4*)&sB3[16 + 4 * q];

#pragma unroll
            for (int t = 0; t < 4; ++t) {
                const int m0 = 64 * wv + 16 * t;
                const float4* xp = (const float4*)(x + (rowbase + m0 + ln) * DD + q * 8);
                float4 uu = xp[0], vv = xp[1];
                union { int4 i; short8 s; } au;
                au.i = make_int4(pkbf(uu.x, uu.y), pkbf(uu.z, uu.w),
                                 pkbf(vv.x, vv.y), pkbf(vv.z, vv.w));

                float4v cA = {0.f,0.f,0.f,0.f}, cB = {0.f,0.f,0.f,0.f};
                cA = __builtin_amdgcn_mfma_f32_16x16x32_bf16(w1a, au.s, cA, 0, 0, 0);
                cB = __builtin_amdgcn_mfma_f32_16x16x32_bf16(w1b, au.s, cB, 0, 0, 0);
                short8 h1f = xpose_h(cA, cB, bA1, bB1, qb, sl_a, sl_b, qlow);

                float4v dA = {0.f,0.f,0.f,0.f}, dB = {0.f,0.f,0.f,0.f};
                dA = __builtin_amdgcn_mfma_f32_16x16x32_bf16(w2a, h1f, dA, 0, 0, 0);
                dB = __builtin_amdgcn_mfma_f32_16x16x32_bf16(w2b, h1f, dB, 0, 0, 0);
                short8 h2f = xpose_h(dA, dB, bA2, bB2, qb, sl_a, sl_b, qlow);

                float4v eA = {0.f,0.f,0.f,0.f}, eB = {0.f,0.f,0.f,0.f};
                eA = __builtin_amdgcn_mfma_f32_16x16x32_bf16(w3a, h2f, eA, 0, 0, 0);
                eB = __builtin_amdgcn_mfma_f32_16x16x32_bf16(w3b, h2f, eB, 0, 0, 0);

                int2 pv0 = make_int2(pkh(eA[0] + bA3.x, eA[1] + bA3.y),
                                     pkh(eA[2] + bA3.z, eA[3] + bA3.w));
                *(int2*)&sP[(m0 + ln) * PSTH + 4 * q] = pv0;
                if (qlow) {
                    int2 pv1 = make_int2(pkh(eB[0] + bB3.x, eB[1] + bB3.y),
                                         pkh(eB[2] + bB3.z, eB[3] + bB3.w));
                    *(int2*)&sP[(m0 + ln) * PSTH + 16 + 4 * q] = pv1;
                }
            }

            // spline: row tid, sP rows written by OWN wave (lgkm-ordered)
            half8v r0 = *(const half8v*)&sP[tid * PSTH];
            half8v r1 = *(const half8v*)&sP[tid * PSTH + 8];
            half8v r2 = *(const half8v*)&sP[tid * PSTH + 16];
            float pr[NPAR];
#pragma unroll
            for (int k = 0; k < 8; ++k) pr[k] = (float)r0[k];
#pragma unroll
            for (int k = 0; k < 8; ++k) pr[8 + k] = (float)r1[k];
#pragma unroll
            for (int k = 0; k < 7; ++k) pr[16 + k] = (float)r2[k];
            z = rqs_apply(xv, pr, ld);
        }
        sZ[tid * ZST + j] = z;
        ldacc += ld;
    }

    float4 z0 = *(const float4*)&sZ[tid * ZST];
    float4 z1 = *(const float4*)&sZ[tid * ZST + 4];
    *(float4*)(zo + row * DD + ly0)     = z0;
    *(float4*)(zo + row * DD + ly0 + 4) = z1;
    unsafeAtomicAdd(&ldo[row], ldacc);
}

// ---- cooperative single-launch kernel: phase0 pack+zero, grid sync, main ----
extern "C" __global__ void __launch_bounds__(TPB, 4)
k_nsf_coop(const float* __restrict__ x, const float* __restrict__ p0,
           const float* __restrict__ w1, const float* __restrict__ b1,
           const float* __restrict__ w2, const float* __restrict__ b2,
           const float* __restrict__ w3, const float* __restrict__ b3,
           char* __restrict__ wbuf, float* __restrict__ zo,
           float* __restrict__ ldo, int B)
{
    __shared__ __align__(16) char sRec[RECB];
    __shared__ __align__(16) _Float16 sP[ROWS * PSTH];
    __shared__ __align__(16) float sZ[ROWS * ZST];

    const int bid = blockIdx.y * gridDim.x + blockIdx.x;
    if (bid < 31)       pack_record(bid, threadIdx.x, w1, b1, w2, b2, w3, b3, wbuf);
    else if (bid < 95)  zero_chunk(bid - 31, threadIdx.x, ldo, B);
    cg::this_grid().sync();
    nsf_body(x, p0, wbuf, zo, ldo, B, sRec, sP, sZ);
}

// ---- fallback pair (if cooperative launch unavailable) ----
extern "C" __global__ void __launch_bounds__(256)
k_prep(const float* __restrict__ w1, const float* __restrict__ b1,
       const float* __restrict__ w2, const float* __restrict__ b2,
       const float* __restrict__ w3, const float* __restrict__ b3,
       char* __restrict__ wbuf, float* __restrict__ ldo, int B)
{
    const int l = blockIdx.x;
    if (l < 31) pack_record(l, threadIdx.x, w1, b1, w2, b2, w3, b3, wbuf);
    else        zero_chunk(l - 31, threadIdx.x, ldo, B);
}

extern "C" __global__ void __launch_bounds__(TPB, 4)
k_nsf_plain(const float* __restrict__ x, const float* __restrict__ p0,
            const char* __restrict__ wbuf, float* __restrict__ zo,
            float* __restrict__ ldo, int B)
{
    __shared__ __align__(16) char sRec[RECB];
    __shared__ __align__(16) _Float16 sP[ROWS * PSTH];
    __shared__ __align__(16) float sZ[ROWS * ZST];
    nsf_body(x, p0, wbuf, zo, ldo, B, sRec, sP, sZ);
}

extern "C" void kernel_launch(void* const* d_in, const int* in_sizes, int n_in,
                              void* d_out, int out_size, void* d_ws, size_t ws_size,
                              hipStream_t stream) {
    const float* x  = (const float*)d_in[0];
    const float* p0 = (const float*)d_in[1];
    const float* w1 = (const float*)d_in[2];
    const float* b1 = (const float*)d_in[3];
    const float* w2 = (const float*)d_in[4];
    const float* b2 = (const float*)d_in[5];
    const float* w3 = (const float*)d_in[6];
    const float* b3 = (const float*)d_in[7];

    const int B = in_sizes[0] / DD;            // 65536
    float* zo  = (float*)d_out;
    float* ldo = zo + (size_t)B * DD;
    char* wbuf = (char*)d_ws;                  // 31 * 8192 B = 254 KB

    void* args[] = {(void*)&x, (void*)&p0, (void*)&w1, (void*)&b1,
                    (void*)&w2, (void*)&b2, (void*)&w3, (void*)&b3,
                    (void*)&wbuf, (void*)&zo, (void*)&ldo, (void*)&B};
    hipError_t err = hipLaunchCooperativeKernel((const void*)k_nsf_coop,
                        dim3(B / ROWS, NGRP), dim3(TPB), args, 0, stream);
    if (err != hipSuccess) {
        (void)hipGetLastError();   // clear sticky error, use 2-dispatch path
        hipLaunchKernelGGL(k_prep, dim3(95), dim3(256), 0, stream,
                           w1, b1, w2, b2, w3, b3, wbuf, ldo, B);
        hipLaunchKernelGGL(k_nsf_plain, dim3(B / ROWS, NGRP), dim3(TPB), 0, stream,
                           x, p0, wbuf, zo, ldo, B);
    }
}

// Round 10
// 151.964 us; speedup vs baseline: 1.4413x; 1.4413x over previous
//
#include <hip/hip_runtime.h>
#include <hip/hip_bf16.h>
#include <cmath>

constexpr int KN   = 8;     // spline knots
constexpr int NPAR = 23;    // 3K-1
constexpr int DD   = 32;    // DIM
constexpr float BND   = 3.0f;
constexpr float MINBW = 1e-3f;
constexpr float MIND  = 1e-3f;

#define TPB   256
#define ROWS  256    // batch rows per block
#define GDIMS 4      // output dims per block (8 groups cover 32)
#define WST   40     // packed W row stride (shorts): 80B, 16B-aligned
#define PSTH  24     // sP row stride (halves): 48B, 16B-aligned, conflict-free
#define RECB  8192   // per-layer packed weight record bytes

typedef __attribute__((ext_vector_type(8))) short short8;      // 8 bf16 (MFMA A/B frag)
typedef __attribute__((ext_vector_type(4))) float float4v;     // MFMA C/D frag
typedef __attribute__((ext_vector_type(2))) __fp16 fp16x2;     // cvt_pkrtz result type
typedef __attribute__((ext_vector_type(8))) _Float16 half8v;

#define RCP(x) __builtin_amdgcn_rcpf(x)

__device__ __forceinline__ short f2bf(float f) {
    unsigned u = __float_as_uint(f);
    u += 0x7fffu + ((u >> 16) & 1u);     // round-to-nearest-even
    return (short)(u >> 16);
}

__device__ __forceinline__ int pkbf(float a, float b) {
    union { __hip_bfloat162 v; int i; } u;
    u.v = __float22bfloat162_rn(make_float2(a, b));
    return u.i;
}

// packed f32x2 -> f16x2 as raw int
__device__ __forceinline__ int pkh(float a, float b) {
    union { fp16x2 h; int i; } u;
    u.h = __builtin_amdgcn_cvt_pkrtz(a, b);
    return u.i;
}

// tanh = 1 - 2/(e^2x + 1): exact at both tails
__device__ __forceinline__ float fast_tanh(float x) {
    float e = __expf(2.0f * x);
    return 1.0f - 2.0f * RCP(e + 1.0f);
}

// softplus for |v| <= ~8: e^v can't overflow
__device__ __forceinline__ float softplus_fast(float v) {
    return __logf(1.0f + __expf(v));
}

// Rational-quadratic spline. p[0:8]=W logits, p[8:16]=H logits, p[16:23]=D
// logits. Only the 2 needed D-logits are gathered in the bin-search chain
// and double-softplus'd (edges pinned to exactly 1.0).
__device__ __forceinline__ float rqs_apply(float xv, const float* p, float& ldout) {
    float cw[KN + 1], ch[KN + 1];
    {
        float t0[KN]; float s = 0.f;
#pragma unroll
        for (int k = 0; k < KN; ++k) { t0[k] = __expf(p[k]); s += t0[k]; }
        float inv = (2.0f * BND) * RCP(s);
        float e2[KN]; float s2 = 0.f;
#pragma unroll
        for (int k = 0; k < KN; ++k) { e2[k] = __expf(inv * t0[k]); s2 += e2[k]; }
        float fac = (1.0f - MINBW * KN) * RCP(s2);
        float c = 0.f;
        cw[0] = -BND;
#pragma unroll
        for (int k = 0; k < KN; ++k) { c += MINBW + fac * e2[k]; cw[k + 1] = 2.0f * BND * c - BND; }
        cw[KN] = BND;
    }
    {
        float t0[KN]; float s = 0.f;
#pragma unroll
        for (int k = 0; k < KN; ++k) { t0[k] = __expf(p[KN + k]); s += t0[k]; }
        float inv = (2.0f * BND) * RCP(s);
        float e2[KN]; float s2 = 0.f;
#pragma unroll
        for (int k = 0; k < KN; ++k) { e2[k] = __expf(inv * t0[k]); s2 += e2[k]; }
        float fac = (1.0f - MINBW * KN) * RCP(s2);
        float c = 0.f;
        ch[0] = -BND;
#pragma unroll
        for (int k = 0; k < KN; ++k) { c += MINBW + fac * e2[k]; ch[k + 1] = 2.0f * BND * c - BND; }
        ch[KN] = BND;
    }

    float xc = fminf(fmaxf(xv, -BND), BND);
    float in_cw = cw[0], in_w = cw[1] - cw[0];
    float in_ch = ch[0], in_h = ch[1] - ch[0];
    float dl0 = 0.0f, dl1 = p[2 * KN];
    bool e0 = true, e1 = false;
#pragma unroll
    for (int k = 1; k < KN; ++k) {
        bool c = (xc >= cw[k]);
        in_cw = c ? cw[k]            : in_cw;
        in_w  = c ? (cw[k+1]-cw[k])  : in_w;
        in_ch = c ? ch[k]            : in_ch;
        in_h  = c ? (ch[k+1]-ch[k])  : in_h;
        dl0   = c ? p[2*KN + k - 1]  : dl0;
        if (k < KN - 1) dl1 = c ? p[2*KN + k] : dl1;
        if (k == 1)      e0 = !c;
        if (k == KN - 1) e1 = c;
    }
    float d0 = e0 ? 1.0f : (MIND + softplus_fast(softplus_fast(dl0)));
    float d1 = e1 ? 1.0f : (MIND + softplus_fast(softplus_fast(dl1)));

    float rw    = RCP(in_w);
    float th    = (xc - in_cw) * rw;
    float delta = in_h * rw;
    float tt    = th * (1.0f - th);
    float th2   = th * th;
    float num   = in_h * (delta * th2 + d0 * tt);
    float den   = delta + (d0 + d1 - 2.0f * delta) * tt;
    float z     = in_ch + num * RCP(den);
    float omt   = 1.0f - th;
    float dnum  = delta * delta * (d1 * th2 + 2.0f * delta * tt + d0 * omt * omt);
    float ldv   = __logf(dnum) - 2.0f * __logf(den);

    bool inside = (xv >= -BND) && (xv <= BND);
    ldout = inside ? ldv : 0.0f;
    return inside ? z : xv;
}

// C-layout -> B-frag cross-lane transpose (register-only, verified R6)
__device__ __forceinline__ short8 xpose_h(float4v cA, float4v cB,
                                          float4 bA, float4 bB,
                                          int odd, int sl_a, int sl_b, bool qlow) {
    int a0 = pkbf(fast_tanh(cA[0] + bA.x), fast_tanh(cA[1] + bA.y));
    int a1 = pkbf(fast_tanh(cA[2] + bA.z), fast_tanh(cA[3] + bA.w));
    int b0 = pkbf(fast_tanh(cB[0] + bB.x), fast_tanh(cB[1] + bB.y));
    int b1 = pkbf(fast_tanh(cB[2] + bB.z), fast_tanh(cB[3] + bB.w));
    int p0 = odd ? b0 : a0, p1 = odd ? b1 : a1;
    int p2 = odd ? a0 : b0, p3 = odd ? a1 : b1;
    int g0 = __shfl(p0, sl_a, 64);
    int g1 = __shfl(p1, sl_a, 64);
    int g2 = __shfl(p2, sl_b, 64);
    int g3 = __shfl(p3, sl_b, 64);
    union { int4 i; short8 s; } u;
    u.i = qlow ? make_int4(g0, g1, g2, g3) : make_int4(g2, g3, g0, g1);
    return u.s;
}

// ---- prep: blocks 0..30 pack per-layer records; blocks 31..94 zero ldo ----
extern "C" __global__ void __launch_bounds__(256)
k_prep(const float* __restrict__ w1, const float* __restrict__ b1,
       const float* __restrict__ w2, const float* __restrict__ b2,
       const float* __restrict__ w3, const float* __restrict__ b3,
       char* __restrict__ wbuf, float* __restrict__ ldo, int B)
{
    const int l = blockIdx.x, tid = threadIdx.x;
    if (l >= 31) {
        const int zb = l - 31;
        const int chunk = B >> 6;
        float4* dst = (float4*)(ldo + (size_t)zb * chunk);
        for (int i = tid; i < (chunk >> 2); i += 256)
            dst[i] = make_float4(0.f, 0.f, 0.f, 0.f);
        return;
    }
    short* r1 = (short*)(wbuf + (size_t)l * RECB);
    short* r2 = r1 + 1280;
    short* r3 = r2 + 1280;
    float* f1 = (float*)(wbuf + (size_t)l * RECB + 7680);
    float* f2 = f1 + 32;
    float* f3 = f2 + 32;
    const float* g1 = w1 + (size_t)l * 992;    // [31][32]
    const float* g2 = w2 + (size_t)l * 1024;   // [32][32]
    const float* g3 = w3 + (size_t)l * 736;    // [32][23]
    for (int i = tid; i < 1280; i += 256) {
        int n = i / WST, k = i - WST * n;
        r1[i] = (k < 31) ? f2bf(g1[k * 32 + n]) : (short)0;
        r2[i] = (k < 32) ? f2bf(g2[k * 32 + n]) : (short)0;
        r3[i] = (n < 23 && k < 32) ? f2bf(g3[k * 23 + n]) : (short)0;
    }
    if (tid < 32) { f1[tid] = b1[(size_t)l * 32 + tid]; f2[tid] = b2[(size_t)l * 32 + tid]; }
    if (tid < 32) f3[tid] = (tid < 23) ? b3[(size_t)l * 23 + tid] : 0.0f;
}

// Block: 256 rows x 4 output dims. Per layer, the 4 per-wave tile chains are
// STAGE-BATCHED (arrays over t) so the scheduler interleaves 4 independent
// MFMA->tanh->shfl chains; launch_bounds(256,5) gives the allocator VGPR
// headroom (R8's min-register schedule at VGPR=36 serialized the chains).
extern "C" __global__ void __launch_bounds__(TPB, 5)
k_nsf(const float* __restrict__ x,
      const float* __restrict__ p0,
      const char* __restrict__ wbuf,
      float* __restrict__ zo, float* __restrict__ ldo, int B)
{
    __shared__ __align__(16) char sRec[RECB];            // one layer record
    __shared__ __align__(16) _Float16 sP[ROWS * PSTH];   // spline params

    const short* sW1 = (const short*)sRec;
    const short* sW2 = sW1 + 1280;
    const short* sW3 = sW1 + 2560;
    const float* sB1 = (const float*)(sRec + 7680);
    const float* sB2 = sB1 + 32;
    const float* sB3 = sB1 + 64;

    const int tid  = threadIdx.x;
    const int lane = tid & 63;
    const int wv   = tid >> 6;
    const int q    = lane >> 4;
    const int ln   = lane & 15;
    const int qb   = q & 1;
    const bool qlow = (q < 2);
    const int s_even = ln + 32 * qb;
    const int s_odd  = s_even + 16;
    const int sl_a = qlow ? s_even : s_odd;
    const int sl_b = qlow ? s_odd  : s_even;
    const int g    = blockIdx.y;
    const int ly0  = GDIMS * g;
    const long long rowbase = (long long)blockIdx.x * ROWS;
    const long long row = rowbase + tid;

    float xarr[GDIMS];
    {
        float4 xs = *(const float4*)(x + row * DD + ly0);
        xarr[0] = xs.x; xarr[1] = xs.y; xarr[2] = xs.z; xarr[3] = xs.w;
    }

    float zreg[GDIMS];
    float ldacc = 0.0f;

#pragma unroll
    for (int j = 0; j < GDIMS; ++j) {
        const int ly = ly0 + j;
        if (ly == 0) {
            float pr[NPAR];
#pragma unroll
            for (int k = 0; k < NPAR; ++k) pr[k] = p0[k];
            float ld;
            zreg[0] = rqs_apply(xarr[0], pr, ld);
            ldacc += ld;
            continue;
        }
        const int l = ly - 1;

        // ---- stage packed record (8192B = 512 int4) ----
        {
            const int4* src = (const int4*)(wbuf + (size_t)l * RECB);
            int4* dst = (int4*)sRec;
            dst[tid]       = src[tid];
            dst[tid + 256] = src[tid + 256];
        }
        __syncthreads();

        short8 w1a = *(const short8*)&sW1[ln * WST + q * 8];
        short8 w1b = *(const short8*)&sW1[(16 + ln) * WST + q * 8];
        short8 w2a = *(const short8*)&sW2[ln * WST + q * 8];
        short8 w2b = *(const short8*)&sW2[(16 + ln) * WST + q * 8];
        short8 w3a = *(const short8*)&sW3[ln * WST + q * 8];
        short8 w3b = *(const short8*)&sW3[(16 + ln) * WST + q * 8];
        float4 bA1 = *(const float4*)&sB1[4 * q];
        float4 bB1 = *(const float4*)&sB1[16 + 4 * q];
        float4 bA2 = *(const float4*)&sB2[4 * q];
        float4 bB2 = *(const float4*)&sB2[16 + 4 * q];
        float4 bA3 = *(const float4*)&sB3[4 * q];
        float4 bB3 = *(const float4*)&sB3[16 + 4 * q];

        // ---- stage A: all 4 tile B-frags from global x ----
        short8 au[4];
#pragma unroll
        for (int t = 0; t < 4; ++t) {
            const int m0 = 64 * wv + 16 * t;
            const float4* xp = (const float4*)(x + (rowbase + m0 + ln) * DD + q * 8);
            float4 uu = xp[0], vv = xp[1];
            union { int4 i; short8 s; } c;
            c.i = make_int4(pkbf(uu.x, uu.y), pkbf(uu.z, uu.w),
                            pkbf(vv.x, vv.y), pkbf(vv.z, vv.w));
            au[t] = c.s;
        }
        // ---- stage B: GEMM1 (8 independent MFMAs) ----
        float4v cA[4], cB[4];
#pragma unroll
        for (int t = 0; t < 4; ++t) {
            float4v zz = {0.f,0.f,0.f,0.f};
            cA[t] = __builtin_amdgcn_mfma_f32_16x16x32_bf16(w1a, au[t], zz, 0, 0, 0);
            cB[t] = __builtin_amdgcn_mfma_f32_16x16x32_bf16(w1b, au[t], zz, 0, 0, 0);
        }
        // ---- stage C: tanh + transpose (32 exps in flight) ----
        short8 h1f[4];
#pragma unroll
        for (int t = 0; t < 4; ++t)
            h1f[t] = xpose_h(cA[t], cB[t], bA1, bB1, qb, sl_a, sl_b, qlow);
        // ---- stage D: GEMM2 ----
#pragma unroll
        for (int t = 0; t < 4; ++t) {
            float4v zz = {0.f,0.f,0.f,0.f};
            cA[t] = __builtin_amdgcn_mfma_f32_16x16x32_bf16(w2a, h1f[t], zz, 0, 0, 0);
            cB[t] = __builtin_amdgcn_mfma_f32_16x16x32_bf16(w2b, h1f[t], zz, 0, 0, 0);
        }
        // ---- stage E: tanh + transpose ----
#pragma unroll
        for (int t = 0; t < 4; ++t)
            h1f[t] = xpose_h(cA[t], cB[t], bA2, bB2, qb, sl_a, sl_b, qlow);
        // ---- stage F: GEMM3 ----
#pragma unroll
        for (int t = 0; t < 4; ++t) {
            float4v zz = {0.f,0.f,0.f,0.f};
            cA[t] = __builtin_amdgcn_mfma_f32_16x16x32_bf16(w3a, h1f[t], zz, 0, 0, 0);
            cB[t] = __builtin_amdgcn_mfma_f32_16x16x32_bf16(w3b, h1f[t], zz, 0, 0, 0);
        }
        // ---- stage G: pack params to sP ----
#pragma unroll
        for (int t = 0; t < 4; ++t) {
            const int m0 = 64 * wv + 16 * t;
            int2 pv0 = make_int2(pkh(cA[t][0] + bA3.x, cA[t][1] + bA3.y),
                                 pkh(cA[t][2] + bA3.z, cA[t][3] + bA3.w));
            *(int2*)&sP[(m0 + ln) * PSTH + 4 * q] = pv0;
            if (qlow) {
                int2 pv1 = make_int2(pkh(cB[t][0] + bB3.x, cB[t][1] + bB3.y),
                                     pkh(cB[t][2] + bB3.z, cB[t][3] + bB3.w));
                *(int2*)&sP[(m0 + ln) * PSTH + 16 + 4 * q] = pv1;
            }
        }

        // ---- spline: thread tid -> row tid (written by OWN wave, lgkm-ordered)
        {
            half8v r0 = *(const half8v*)&sP[tid * PSTH];
            half8v r1 = *(const half8v*)&sP[tid * PSTH + 8];
            half8v r2 = *(const half8v*)&sP[tid * PSTH + 16];
            float pr[NPAR];
#pragma unroll
            for (int k = 0; k < 8; ++k) pr[k] = (float)r0[k];
#pragma unroll
            for (int k = 0; k < 8; ++k) pr[8 + k] = (float)r1[k];
#pragma unroll
            for (int k = 0; k < 7; ++k) pr[16 + k] = (float)r2[k];
            float ld;
            zreg[j] = rqs_apply(xarr[j], pr, ld);
            ldacc += ld;
        }
        __syncthreads();   // protect sRec/sP before next layer
    }

    float4 zv = make_float4(zreg[0], zreg[1], zreg[2], zreg[3]);
    *(float4*)(zo + row * DD + ly0) = zv;
    unsafeAtomicAdd(&ldo[row], ldacc);
}

extern "C" void kernel_launch(void* const* d_in, const int* in_sizes, int n_in,
                              void* d_out, int out_size, void* d_ws, size_t ws_size,
                              hipStream_t stream) {
    const float* x  = (const float*)d_in[0];
    const float* p0 = (const float*)d_in[1];
    const float* w1 = (const float*)d_in[2];
    const float* b1 = (const float*)d_in[3];
    const float* w2 = (const float*)d_in[4];
    const float* b2 = (const float*)d_in[5];
    const float* w3 = (const float*)d_in[6];
    const float* b3 = (const float*)d_in[7];

    const int B = in_sizes[0] / DD;            // 65536
    float* zo  = (float*)d_out;
    float* ldo = zo + (size_t)B * DD;
    char* wbuf = (char*)d_ws;                  // 31 * 8192 B = 254 KB

    hipLaunchKernelGGL(k_prep, dim3(95), dim3(256), 0, stream,
                       w1, b1, w2, b2, w3, b3, wbuf, ldo, B);
    hipLaunchKernelGGL(k_nsf, dim3(B / ROWS, DD / GDIMS), dim3(TPB), 0, stream,
                       x, p0, wbuf, zo, ldo, B);
}

// Round 11
// 147.918 us; speedup vs baseline: 1.4807x; 1.0274x over previous
//
#include <hip/hip_runtime.h>
#include <hip/hip_bf16.h>
#include <cmath>

constexpr int KN   = 8;     // spline knots
constexpr int NPAR = 23;    // 3K-1
constexpr int DD   = 32;    // DIM
constexpr float BND   = 3.0f;
constexpr float MINBW = 1e-3f;
constexpr float MIND  = 1e-3f;

#define TPB   256
#define ROWS  256    // batch rows per block
#define GDIMS 4      // output dims per block (8 groups cover 32)
#define WST   40     // packed W row stride (shorts): 80B, 16B-aligned
#define PSTH  28     // sP row stride (halves): 56B, b64-aligned, <=4-way banks
#define RECB  8192   // per-layer packed weight record bytes

typedef __attribute__((ext_vector_type(8))) short short8;      // 8 bf16 (MFMA A/B frag)
typedef __attribute__((ext_vector_type(4))) float float4v;     // MFMA C/D frag
typedef __attribute__((ext_vector_type(2))) __fp16 fp16x2;     // cvt_pkrtz result type
typedef __attribute__((ext_vector_type(4))) _Float16 half4v;   // 8B LDS load

#define RCP(x) __builtin_amdgcn_rcpf(x)

__device__ __forceinline__ short f2bf(float f) {
    unsigned u = __float_as_uint(f);
    u += 0x7fffu + ((u >> 16) & 1u);     // round-to-nearest-even
    return (short)(u >> 16);
}

__device__ __forceinline__ int pkbf(float a, float b) {
    union { __hip_bfloat162 v; int i; } u;
    u.v = __float22bfloat162_rn(make_float2(a, b));
    return u.i;
}

// packed f32x2 -> f16x2 as raw int
__device__ __forceinline__ int pkh(float a, float b) {
    union { fp16x2 h; int i; } u;
    u.h = __builtin_amdgcn_cvt_pkrtz(a, b);
    return u.i;
}

// tanh = 1 - 2/(e^2x + 1): exact at both tails
__device__ __forceinline__ float fast_tanh(float x) {
    float e = __expf(2.0f * x);
    return 1.0f - 2.0f * RCP(e + 1.0f);
}

// softplus for |v| <= ~8: e^v can't overflow
__device__ __forceinline__ float softplus_fast(float v) {
    return __logf(1.0f + __expf(v));
}

// Rational-quadratic spline. p[0:8]=W logits, p[8:16]=H logits, p[16:23]=D
// logits. Only the 2 needed D-logits are gathered in the bin-search chain
// and double-softplus'd (edges pinned to exactly 1.0).
__device__ __forceinline__ float rqs_apply(float xv, const float* p, float& ldout) {
    float cw[KN + 1], ch[KN + 1];
    {
        float t0[KN]; float s = 0.f;
#pragma unroll
        for (int k = 0; k < KN; ++k) { t0[k] = __expf(p[k]); s += t0[k]; }
        float inv = (2.0f * BND) * RCP(s);
        float e2[KN]; float s2 = 0.f;
#pragma unroll
        for (int k = 0; k < KN; ++k) { e2[k] = __expf(inv * t0[k]); s2 += e2[k]; }
        float fac = (1.0f - MINBW * KN) * RCP(s2);
        float c = 0.f;
        cw[0] = -BND;
#pragma unroll
        for (int k = 0; k < KN; ++k) { c += MINBW + fac * e2[k]; cw[k + 1] = 2.0f * BND * c - BND; }
        cw[KN] = BND;
    }
    {
        float t0[KN]; float s = 0.f;
#pragma unroll
        for (int k = 0; k < KN; ++k) { t0[k] = __expf(p[KN + k]); s += t0[k]; }
        float inv = (2.0f * BND) * RCP(s);
        float e2[KN]; float s2 = 0.f;
#pragma unroll
        for (int k = 0; k < KN; ++k) { e2[k] = __expf(inv * t0[k]); s2 += e2[k]; }
        float fac = (1.0f - MINBW * KN) * RCP(s2);
        float c = 0.f;
        ch[0] = -BND;
#pragma unroll
        for (int k = 0; k < KN; ++k) { c += MINBW + fac * e2[k]; ch[k + 1] = 2.0f * BND * c - BND; }
        ch[KN] = BND;
    }

    float xc = fminf(fmaxf(xv, -BND), BND);
    float in_cw = cw[0], in_w = cw[1] - cw[0];
    float in_ch = ch[0], in_h = ch[1] - ch[0];
    float dl0 = 0.0f, dl1 = p[2 * KN];
    bool e0 = true, e1 = false;
#pragma unroll
    for (int k = 1; k < KN; ++k) {
        bool c = (xc >= cw[k]);
        in_cw = c ? cw[k]            : in_cw;
        in_w  = c ? (cw[k+1]-cw[k])  : in_w;
        in_ch = c ? ch[k]            : in_ch;
        in_h  = c ? (ch[k+1]-ch[k])  : in_h;
        dl0   = c ? p[2*KN + k - 1]  : dl0;
        if (k < KN - 1) dl1 = c ? p[2*KN + k] : dl1;
        if (k == 1)      e0 = !c;
        if (k == KN - 1) e1 = c;
    }
    float d0 = e0 ? 1.0f : (MIND + softplus_fast(softplus_fast(dl0)));
    float d1 = e1 ? 1.0f : (MIND + softplus_fast(softplus_fast(dl1)));

    float rw    = RCP(in_w);
    float th    = (xc - in_cw) * rw;
    float delta = in_h * rw;
    float tt    = th * (1.0f - th);
    float th2   = th * th;
    float num   = in_h * (delta * th2 + d0 * tt);
    float den   = delta + (d0 + d1 - 2.0f * delta) * tt;
    float z     = in_ch + num * RCP(den);
    float omt   = 1.0f - th;
    float dnum  = delta * delta * (d1 * th2 + 2.0f * delta * tt + d0 * omt * omt);
    float ldv   = __logf(dnum) - 2.0f * __logf(den);

    bool inside = (xv >= -BND) && (xv <= BND);
    ldout = inside ? ldv : 0.0f;
    return inside ? z : xv;
}

// C-layout -> B-frag cross-lane transpose (register-only, verified R6).
// Bias is already folded into the MFMA accumulator -> pure tanh here.
__device__ __forceinline__ short8 xpose_h(float4v cA, float4v cB,
                                          int odd, int sl_a, int sl_b, bool qlow) {
    int a0 = pkbf(fast_tanh(cA[0]), fast_tanh(cA[1]));
    int a1 = pkbf(fast_tanh(cA[2]), fast_tanh(cA[3]));
    int b0 = pkbf(fast_tanh(cB[0]), fast_tanh(cB[1]));
    int b1 = pkbf(fast_tanh(cB[2]), fast_tanh(cB[3]));
    int p0 = odd ? b0 : a0, p1 = odd ? b1 : a1;
    int p2 = odd ? a0 : b0, p3 = odd ? a1 : b1;
    int g0 = __shfl(p0, sl_a, 64);
    int g1 = __shfl(p1, sl_a, 64);
    int g2 = __shfl(p2, sl_b, 64);
    int g3 = __shfl(p3, sl_b, 64);
    union { int4 i; short8 s; } u;
    u.i = qlow ? make_int4(g0, g1, g2, g3) : make_int4(g2, g3, g0, g1);
    return u.s;
}

__device__ __forceinline__ float4v f4v(float4 v) {
    float4v r; r[0] = v.x; r[1] = v.y; r[2] = v.z; r[3] = v.w; return r;
}

// ---- prep: blocks 0..30 pack per-layer records; blocks 31..94 zero ldo ----
extern "C" __global__ void __launch_bounds__(256)
k_prep(const float* __restrict__ w1, const float* __restrict__ b1,
       const float* __restrict__ w2, const float* __restrict__ b2,
       const float* __restrict__ w3, const float* __restrict__ b3,
       char* __restrict__ wbuf, float* __restrict__ ldo, int B)
{
    const int l = blockIdx.x, tid = threadIdx.x;
    if (l >= 31) {
        const int zb = l - 31;
        const int chunk = B >> 6;
        float4* dst = (float4*)(ldo + (size_t)zb * chunk);
        for (int i = tid; i < (chunk >> 2); i += 256)
            dst[i] = make_float4(0.f, 0.f, 0.f, 0.f);
        return;
    }
    short* r1 = (short*)(wbuf + (size_t)l * RECB);
    short* r2 = r1 + 1280;
    short* r3 = r2 + 1280;
    float* f1 = (float*)(wbuf + (size_t)l * RECB + 7680);
    float* f2 = f1 + 32;
    float* f3 = f2 + 32;
    const float* g1 = w1 + (size_t)l * 992;    // [31][32]
    const float* g2 = w2 + (size_t)l * 1024;   // [32][32]
    const float* g3 = w3 + (size_t)l * 736;    // [32][23]
    for (int i = tid; i < 1280; i += 256) {
        int n = i / WST, k = i - WST * n;
        r1[i] = (k < 31) ? f2bf(g1[k * 32 + n]) : (short)0;
        r2[i] = (k < 32) ? f2bf(g2[k * 32 + n]) : (short)0;
        r3[i] = (n < 23 && k < 32) ? f2bf(g3[k * 23 + n]) : (short)0;
    }
    if (tid < 32) { f1[tid] = b1[(size_t)l * 32 + tid]; f2[tid] = b2[(size_t)l * 32 + tid]; }
    if (tid < 32) f3[tid] = (tid < 23) ? b3[(size_t)l * 23 + tid] : 0.0f;
}

// Block: 256 rows x 4 output dims. ZERO barriers: weights/biases read per-lane
// directly from L2-resident wbuf; sP is per-wave-private (wave wv touches only
// rows [64wv,64wv+64)); x B-frags hoisted out of the layer loop; biases folded
// into MFMA accumulator init.
extern "C" __global__ void __launch_bounds__(TPB, 5)
k_nsf(const float* __restrict__ x,
      const float* __restrict__ p0,
      const char* __restrict__ wbuf,
      float* __restrict__ zo, float* __restrict__ ldo, int B)
{
    __shared__ __align__(16) _Float16 sP[ROWS * PSTH];   // spline params

    const int tid  = threadIdx.x;
    const int lane = tid & 63;
    const int wv   = tid >> 6;
    const int q    = lane >> 4;
    const int ln   = lane & 15;
    const int qb   = q & 1;
    const bool qlow = (q < 2);
    const int s_even = ln + 32 * qb;
    const int s_odd  = s_even + 16;
    const int sl_a = qlow ? s_even : s_odd;
    const int sl_b = qlow ? s_odd  : s_even;
    const int g    = blockIdx.y;
    const int ly0  = GDIMS * g;
    const long long rowbase = (long long)blockIdx.x * ROWS;
    const long long row = rowbase + tid;

    // own-row spline inputs (one float4)
    float xarr[GDIMS];
    {
        float4 xs = *(const float4*)(x + row * DD + ly0);
        xarr[0] = xs.x; xarr[1] = xs.y; xarr[2] = xs.z; xarr[3] = xs.w;
    }

    // hoisted: x B-frags for all 4 tiles (layer-invariant!)
    short8 au[4];
#pragma unroll
    for (int t = 0; t < 4; ++t) {
        const int m0 = 64 * wv + 16 * t;
        const float4* xp = (const float4*)(x + (rowbase + m0 + ln) * DD + q * 8);
        float4 uu = xp[0], vv = xp[1];
        union { int4 i; short8 s; } c;
        c.i = make_int4(pkbf(uu.x, uu.y), pkbf(uu.z, uu.w),
                        pkbf(vv.x, vv.y), pkbf(vv.z, vv.w));
        au[t] = c.s;
    }

    float zreg[GDIMS];
    float ldacc = 0.0f;

#pragma unroll
    for (int j = 0; j < GDIMS; ++j) {
        const int ly = ly0 + j;
        if (ly == 0) {
            float pr[NPAR];
#pragma unroll
            for (int k = 0; k < NPAR; ++k) pr[k] = p0[k];
            float ld;
            zreg[0] = rqs_apply(xarr[0], pr, ld);
            ldacc += ld;
            continue;
        }
        const int l = ly - 1;
        const char* rec = wbuf + (size_t)l * RECB;
        const short* rw = (const short*)rec;
        const float* rb = (const float*)(rec + 7680);

        // per-lane weight frags + biases straight from L2
        short8 w1a = *(const short8*)&rw[ln * WST + q * 8];
        short8 w1b = *(const short8*)&rw[(16 + ln) * WST + q * 8];
        short8 w2a = *(const short8*)&rw[1280 + ln * WST + q * 8];
        short8 w2b = *(const short8*)&rw[1280 + (16 + ln) * WST + q * 8];
        short8 w3a = *(const short8*)&rw[2560 + ln * WST + q * 8];
        short8 w3b = *(const short8*)&rw[2560 + (16 + ln) * WST + q * 8];
        float4v bA1 = f4v(*(const float4*)&rb[4 * q]);
        float4v bB1 = f4v(*(const float4*)&rb[16 + 4 * q]);
        float4v bA2 = f4v(*(const float4*)&rb[32 + 4 * q]);
        float4v bB2 = f4v(*(const float4*)&rb[48 + 4 * q]);
        float4v bA3 = f4v(*(const float4*)&rb[64 + 4 * q]);
        float4v bB3 = f4v(*(const float4*)&rb[80 + 4 * q]);

        // ---- GEMM1 (bias as accumulator init) ----
        float4v cA[4], cB[4];
#pragma unroll
        for (int t = 0; t < 4; ++t) {
            cA[t] = __builtin_amdgcn_mfma_f32_16x16x32_bf16(w1a, au[t], bA1, 0, 0, 0);
            cB[t] = __builtin_amdgcn_mfma_f32_16x16x32_bf16(w1b, au[t], bB1, 0, 0, 0);
        }
        // ---- tanh + transpose (4 independent chains) ----
        short8 h1f[4];
#pragma unroll
        for (int t = 0; t < 4; ++t)
            h1f[t] = xpose_h(cA[t], cB[t], qb, sl_a, sl_b, qlow);
        // ---- GEMM2 ----
#pragma unroll
        for (int t = 0; t < 4; ++t) {
            cA[t] = __builtin_amdgcn_mfma_f32_16x16x32_bf16(w2a, h1f[t], bA2, 0, 0, 0);
            cB[t] = __builtin_amdgcn_mfma_f32_16x16x32_bf16(w2b, h1f[t], bB2, 0, 0, 0);
        }
        // ---- tanh + transpose ----
#pragma unroll
        for (int t = 0; t < 4; ++t)
            h1f[t] = xpose_h(cA[t], cB[t], qb, sl_a, sl_b, qlow);
        // ---- GEMM3 (b3 folded) ----
#pragma unroll
        for (int t = 0; t < 4; ++t) {
            cA[t] = __builtin_amdgcn_mfma_f32_16x16x32_bf16(w3a, h1f[t], bA3, 0, 0, 0);
            cB[t] = __builtin_amdgcn_mfma_f32_16x16x32_bf16(w3b, h1f[t], bB3, 0, 0, 0);
        }
        // ---- pack params to per-wave sP ----
#pragma unroll
        for (int t = 0; t < 4; ++t) {
            const int m0 = 64 * wv + 16 * t;
            int2 pv0 = make_int2(pkh(cA[t][0], cA[t][1]), pkh(cA[t][2], cA[t][3]));
            *(int2*)&sP[(m0 + ln) * PSTH + 4 * q] = pv0;
            if (qlow) {
                int2 pv1 = make_int2(pkh(cB[t][0], cB[t][1]), pkh(cB[t][2], cB[t][3]));
                *(int2*)&sP[(m0 + ln) * PSTH + 16 + 4 * q] = pv1;
            }
        }

        // ---- spline: row tid, sP rows written by OWN wave (lgkm-ordered) ----
        {
            const _Float16* pp = &sP[tid * PSTH];
            float pr[24];
#pragma unroll
            for (int u = 0; u < 6; ++u) {
                half4v hv = *(const half4v*)(pp + 4 * u);
                pr[4*u+0] = (float)hv[0];
                pr[4*u+1] = (float)hv[1];
                pr[4*u+2] = (float)hv[2];
                pr[4*u+3] = (float)hv[3];
            }
            float ld;
            zreg[j] = rqs_apply(xarr[j], pr, ld);
            ldacc += ld;
        }
        // no barrier: sP rows are wave-private; same-wave DS ordering suffices
    }

    float4 zv = make_float4(zreg[0], zreg[1], zreg[2], zreg[3]);
    *(float4*)(zo + row * DD + ly0) = zv;
    unsafeAtomicAdd(&ldo[row], ldacc);
}

extern "C" void kernel_launch(void* const* d_in, const int* in_sizes, int n_in,
                              void* d_out, int out_size, void* d_ws, size_t ws_size,
                              hipStream_t stream) {
    const float* x  = (const float*)d_in[0];
    const float* p0 = (const float*)d_in[1];
    const float* w1 = (const float*)d_in[2];
    const float* b1 = (const float*)d_in[3];
    const float* w2 = (const float*)d_in[4];
    const float* b2 = (const float*)d_in[5];
    const float* w3 = (const float*)d_in[6];
    const float* b3 = (const float*)d_in[7];

    const int B = in_sizes[0] / DD;            // 65536
    float* zo  = (float*)d_out;
    float* ldo = zo + (size_t)B * DD;
    char* wbuf = (char*)d_ws;                  // 31 * 8192 B = 254 KB

    hipLaunchKernelGGL(k_prep, dim3(95), dim3(256), 0, stream,
                       w1, b1, w2, b2, w3, b3, wbuf, ldo, B);
    hipLaunchKernelGGL(k_nsf, dim3(B / ROWS, DD / GDIMS), dim3(TPB), 0, stream,
                       x, p0, wbuf, zo, ldo, B);
}

// Round 12
// 143.358 us; speedup vs baseline: 1.5278x; 1.0318x over previous
//
#include <hip/hip_runtime.h>
#include <hip/hip_bf16.h>
#include <cmath>

constexpr int KN   = 8;     // spline knots
constexpr int NPAR = 23;    // 3K-1
constexpr int DD   = 32;    // DIM
constexpr float BND   = 3.0f;
constexpr float MINBW = 1e-3f;
constexpr float MIND  = 1e-3f;

#define TPB   256
#define ROWS  256    // batch rows per block
#define GDIMS 4      // output dims per block (8 groups cover 32)
#define WST   40     // packed W row stride (shorts): 80B, 16B-aligned
#define PSTH  28     // sP row stride (halves): 56B, b64-aligned, <=4-way banks
#define RECB  8192   // per-layer packed weight record bytes

typedef __attribute__((ext_vector_type(8))) short short8;      // 8 bf16 (MFMA A/B frag)
typedef __attribute__((ext_vector_type(4))) float float4v;     // MFMA C/D frag
typedef __attribute__((ext_vector_type(2))) __fp16 fp16x2;     // cvt_pkrtz result type
typedef __attribute__((ext_vector_type(4))) _Float16 half4v;   // 8B LDS load

#define RCP(x) __builtin_amdgcn_rcpf(x)

__device__ __forceinline__ short f2bf(float f) {
    unsigned u = __float_as_uint(f);
    u += 0x7fffu + ((u >> 16) & 1u);     // round-to-nearest-even
    return (short)(u >> 16);
}

__device__ __forceinline__ int pkbf(float a, float b) {
    union { __hip_bfloat162 v; int i; } u;
    u.v = __float22bfloat162_rn(make_float2(a, b));
    return u.i;
}

// packed f32x2 -> f16x2 as raw int
__device__ __forceinline__ int pkh(float a, float b) {
    union { fp16x2 h; int i; } u;
    u.h = __builtin_amdgcn_cvt_pkrtz(a, b);
    return u.i;
}

// tanh = 1 - 2/(e^2x + 1): exact at both tails
__device__ __forceinline__ float fast_tanh(float x) {
    float e = __expf(2.0f * x);
    return 1.0f - 2.0f * RCP(e + 1.0f);
}

// softplus for |v| <= ~8: e^v can't overflow
__device__ __forceinline__ float softplus_fast(float v) {
    return __logf(1.0f + __expf(v));
}

// Rational-quadratic spline. p[0:8]=W logits, p[8:16]=H logits, p[16:23]=D
// logits. Only the 2 needed D-logits are gathered in the bin-search chain
// and double-softplus'd (edges pinned to exactly 1.0).
__device__ __forceinline__ float rqs_apply(float xv, const float* p, float& ldout) {
    float cw[KN + 1], ch[KN + 1];
    {
        float t0[KN]; float s = 0.f;
#pragma unroll
        for (int k = 0; k < KN; ++k) { t0[k] = __expf(p[k]); s += t0[k]; }
        float inv = (2.0f * BND) * RCP(s);
        float e2[KN]; float s2 = 0.f;
#pragma unroll
        for (int k = 0; k < KN; ++k) { e2[k] = __expf(inv * t0[k]); s2 += e2[k]; }
        float fac = (1.0f - MINBW * KN) * RCP(s2);
        float c = 0.f;
        cw[0] = -BND;
#pragma unroll
        for (int k = 0; k < KN; ++k) { c += MINBW + fac * e2[k]; cw[k + 1] = 2.0f * BND * c - BND; }
        cw[KN] = BND;
    }
    {
        float t0[KN]; float s = 0.f;
#pragma unroll
        for (int k = 0; k < KN; ++k) { t0[k] = __expf(p[KN + k]); s += t0[k]; }
        float inv = (2.0f * BND) * RCP(s);
        float e2[KN]; float s2 = 0.f;
#pragma unroll
        for (int k = 0; k < KN; ++k) { e2[k] = __expf(inv * t0[k]); s2 += e2[k]; }
        float fac = (1.0f - MINBW * KN) * RCP(s2);
        float c = 0.f;
        ch[0] = -BND;
#pragma unroll
        for (int k = 0; k < KN; ++k) { c += MINBW + fac * e2[k]; ch[k + 1] = 2.0f * BND * c - BND; }
        ch[KN] = BND;
    }

    float xc = fminf(fmaxf(xv, -BND), BND);
    float in_cw = cw[0], in_w = cw[1] - cw[0];
    float in_ch = ch[0], in_h = ch[1] - ch[0];
    float dl0 = 0.0f, dl1 = p[2 * KN];
    bool e0 = true, e1 = false;
#pragma unroll
    for (int k = 1; k < KN; ++k) {
        bool c = (xc >= cw[k]);
        in_cw = c ? cw[k]            : in_cw;
        in_w  = c ? (cw[k+1]-cw[k])  : in_w;
        in_ch = c ? ch[k]            : in_ch;
        in_h  = c ? (ch[k+1]-ch[k])  : in_h;
        dl0   = c ? p[2*KN + k - 1]  : dl0;
        if (k < KN - 1) dl1 = c ? p[2*KN + k] : dl1;
        if (k == 1)      e0 = !c;
        if (k == KN - 1) e1 = c;
    }
    float d0 = e0 ? 1.0f : (MIND + softplus_fast(softplus_fast(dl0)));
    float d1 = e1 ? 1.0f : (MIND + softplus_fast(softplus_fast(dl1)));

    float rw    = RCP(in_w);
    float th    = (xc - in_cw) * rw;
    float delta = in_h * rw;
    float tt    = th * (1.0f - th);
    float th2   = th * th;
    float num   = in_h * (delta * th2 + d0 * tt);
    float den   = delta + (d0 + d1 - 2.0f * delta) * tt;
    float z     = in_ch + num * RCP(den);
    float omt   = 1.0f - th;
    float dnum  = delta * delta * (d1 * th2 + 2.0f * delta * tt + d0 * omt * omt);
    float ldv   = __logf(dnum) - 2.0f * __logf(den);

    bool inside = (xv >= -BND) && (xv <= BND);
    ldout = inside ? ldv : 0.0f;
    return inside ? z : xv;
}

// C-layout -> B-frag cross-lane transpose (register-only, verified R6).
__device__ __forceinline__ short8 xpose_h(float4v cA, float4v cB,
                                          int odd, int sl_a, int sl_b, bool qlow) {
    int a0 = pkbf(fast_tanh(cA[0]), fast_tanh(cA[1]));
    int a1 = pkbf(fast_tanh(cA[2]), fast_tanh(cA[3]));
    int b0 = pkbf(fast_tanh(cB[0]), fast_tanh(cB[1]));
    int b1 = pkbf(fast_tanh(cB[2]), fast_tanh(cB[3]));
    int p0 = odd ? b0 : a0, p1 = odd ? b1 : a1;
    int p2 = odd ? a0 : b0, p3 = odd ? a1 : b1;
    int g0 = __shfl(p0, sl_a, 64);
    int g1 = __shfl(p1, sl_a, 64);
    int g2 = __shfl(p2, sl_b, 64);
    int g3 = __shfl(p3, sl_b, 64);
    union { int4 i; short8 s; } u;
    u.i = qlow ? make_int4(g0, g1, g2, g3) : make_int4(g2, g3, g0, g1);
    return u.s;
}

__device__ __forceinline__ float4v f4v(float4 v) {
    float4v r; r[0] = v.x; r[1] = v.y; r[2] = v.z; r[3] = v.w; return r;
}

// per-lane weight/bias fragments for one layer (48 VGPRs live)
struct WFrag {
    short8 w1a, w1b, w2a, w2b, w3a, w3b;
    float4v bA1, bB1, bA2, bB2, bA3, bB3;
};

__device__ __forceinline__ WFrag load_wfrag(const char* __restrict__ wbuf,
                                            int l, int ln, int q) {
    const char* rec = wbuf + (size_t)l * RECB;
    const short* rw = (const short*)rec;
    const float* rb = (const float*)(rec + 7680);
    WFrag f;
    f.w1a = *(const short8*)&rw[ln * WST + q * 8];
    f.w1b = *(const short8*)&rw[(16 + ln) * WST + q * 8];
    f.w2a = *(const short8*)&rw[1280 + ln * WST + q * 8];
    f.w2b = *(const short8*)&rw[1280 + (16 + ln) * WST + q * 8];
    f.w3a = *(const short8*)&rw[2560 + ln * WST + q * 8];
    f.w3b = *(const short8*)&rw[2560 + (16 + ln) * WST + q * 8];
    f.bA1 = f4v(*(const float4*)&rb[4 * q]);
    f.bB1 = f4v(*(const float4*)&rb[16 + 4 * q]);
    f.bA2 = f4v(*(const float4*)&rb[32 + 4 * q]);
    f.bB2 = f4v(*(const float4*)&rb[48 + 4 * q]);
    f.bA3 = f4v(*(const float4*)&rb[64 + 4 * q]);
    f.bB3 = f4v(*(const float4*)&rb[80 + 4 * q]);
    return f;
}

// ---- prep: blocks 0..30 pack per-layer records; blocks 31..94 zero ldo ----
extern "C" __global__ void __launch_bounds__(256)
k_prep(const float* __restrict__ w1, const float* __restrict__ b1,
       const float* __restrict__ w2, const float* __restrict__ b2,
       const float* __restrict__ w3, const float* __restrict__ b3,
       char* __restrict__ wbuf, float* __restrict__ ldo, int B)
{
    const int l = blockIdx.x, tid = threadIdx.x;
    if (l >= 31) {
        const int zb = l - 31;
        const int chunk = B >> 6;
        float4* dst = (float4*)(ldo + (size_t)zb * chunk);
        for (int i = tid; i < (chunk >> 2); i += 256)
            dst[i] = make_float4(0.f, 0.f, 0.f, 0.f);
        return;
    }
    short* r1 = (short*)(wbuf + (size_t)l * RECB);
    short* r2 = r1 + 1280;
    short* r3 = r2 + 1280;
    float* f1 = (float*)(wbuf + (size_t)l * RECB + 7680);
    float* f2 = f1 + 32;
    float* f3 = f2 + 32;
    const float* g1 = w1 + (size_t)l * 992;    // [31][32]
    const float* g2 = w2 + (size_t)l * 1024;   // [32][32]
    const float* g3 = w3 + (size_t)l * 736;    // [32][23]
    for (int i = tid; i < 1280; i += 256) {
        int n = i / WST, k = i - WST * n;
        r1[i] = (k < 31) ? f2bf(g1[k * 32 + n]) : (short)0;
        r2[i] = (k < 32) ? f2bf(g2[k * 32 + n]) : (short)0;
        r3[i] = (n < 23 && k < 32) ? f2bf(g3[k * 23 + n]) : (short)0;
    }
    if (tid < 32) { f1[tid] = b1[(size_t)l * 32 + tid]; f2[tid] = b2[(size_t)l * 32 + tid]; }
    if (tid < 32) f3[tid] = (tid < 23) ? b3[(size_t)l * 23 + tid] : 0.0f;
}

// Block: 256 rows x 4 output dims. Zero barriers; weights per-lane from L2;
// sP wave-private; x B-frags hoisted. launch_bounds(256,3): give the register
// allocator ~170 VGPRs so the 4 tile chains + prefetched next-layer weights
// stay live (at VGPR=48 the allocator serializes the chains — R10/R11).
extern "C" __global__ void __launch_bounds__(TPB, 3)
k_nsf(const float* __restrict__ x,
      const float* __restrict__ p0,
      const char* __restrict__ wbuf,
      float* __restrict__ zo, float* __restrict__ ldo, int B)
{
    __shared__ __align__(16) _Float16 sP[ROWS * PSTH];   // spline params

    const int tid  = threadIdx.x;
    const int lane = tid & 63;
    const int wv   = tid >> 6;
    const int q    = lane >> 4;
    const int ln   = lane & 15;
    const int qb   = q & 1;
    const bool qlow = (q < 2);
    const int s_even = ln + 32 * qb;
    const int s_odd  = s_even + 16;
    const int sl_a = qlow ? s_even : s_odd;
    const int sl_b = qlow ? s_odd  : s_even;
    const int g    = blockIdx.y;
    const int ly0  = GDIMS * g;
    const long long rowbase = (long long)blockIdx.x * ROWS;
    const long long row = rowbase + tid;

    // own-row spline inputs (one float4)
    float xarr[GDIMS];
    {
        float4 xs = *(const float4*)(x + row * DD + ly0);
        xarr[0] = xs.x; xarr[1] = xs.y; xarr[2] = xs.z; xarr[3] = xs.w;
    }

    // hoisted: x B-frags for all 4 tiles (layer-invariant)
    short8 au[4];
#pragma unroll
    for (int t = 0; t < 4; ++t) {
        const int m0 = 64 * wv + 16 * t;
        const float4* xp = (const float4*)(x + (rowbase + m0 + ln) * DD + q * 8);
        float4 uu = xp[0], vv = xp[1];
        union { int4 i; short8 s; } c;
        c.i = make_int4(pkbf(uu.x, uu.y), pkbf(uu.z, uu.w),
                        pkbf(vv.x, vv.y), pkbf(vv.z, vv.w));
        au[t] = c.s;
    }

    float zreg[GDIMS];
    float ldacc = 0.0f;

    // prefetch first conditioner layer's weights
    WFrag wf = load_wfrag(wbuf, (ly0 == 0) ? 0 : ly0 - 1, ln, q);

#pragma unroll
    for (int j = 0; j < GDIMS; ++j) {
        const int ly = ly0 + j;
        if (ly == 0) {
            // init_param spline (wf for layer 0 already in flight)
            float pr[NPAR];
#pragma unroll
            for (int k = 0; k < NPAR; ++k) pr[k] = p0[k];
            float ld;
            zreg[0] = rqs_apply(xarr[0], pr, ld);
            ldacc += ld;
            continue;
        }

        // ---- GEMM1 (bias folded into accumulator) ----
        float4v cA[4], cB[4];
#pragma unroll
        for (int t = 0; t < 4; ++t) {
            cA[t] = __builtin_amdgcn_mfma_f32_16x16x32_bf16(wf.w1a, au[t], wf.bA1, 0, 0, 0);
            cB[t] = __builtin_amdgcn_mfma_f32_16x16x32_bf16(wf.w1b, au[t], wf.bB1, 0, 0, 0);
        }
        short8 h1f[4];
#pragma unroll
        for (int t = 0; t < 4; ++t)
            h1f[t] = xpose_h(cA[t], cB[t], qb, sl_a, sl_b, qlow);
        // ---- GEMM2 ----
#pragma unroll
        for (int t = 0; t < 4; ++t) {
            cA[t] = __builtin_amdgcn_mfma_f32_16x16x32_bf16(wf.w2a, h1f[t], wf.bA2, 0, 0, 0);
            cB[t] = __builtin_amdgcn_mfma_f32_16x16x32_bf16(wf.w2b, h1f[t], wf.bB2, 0, 0, 0);
        }
#pragma unroll
        for (int t = 0; t < 4; ++t)
            h1f[t] = xpose_h(cA[t], cB[t], qb, sl_a, sl_b, qlow);
        // ---- GEMM3 ----
#pragma unroll
        for (int t = 0; t < 4; ++t) {
            cA[t] = __builtin_amdgcn_mfma_f32_16x16x32_bf16(wf.w3a, h1f[t], wf.bA3, 0, 0, 0);
            cB[t] = __builtin_amdgcn_mfma_f32_16x16x32_bf16(wf.w3b, h1f[t], wf.bB3, 0, 0, 0);
        }
        // ---- pack params to per-wave sP ----
#pragma unroll
        for (int t = 0; t < 4; ++t) {
            const int m0 = 64 * wv + 16 * t;
            int2 pv0 = make_int2(pkh(cA[t][0], cA[t][1]), pkh(cA[t][2], cA[t][3]));
            *(int2*)&sP[(m0 + ln) * PSTH + 4 * q] = pv0;
            if (qlow) {
                int2 pv1 = make_int2(pkh(cB[t][0], cB[t][1]), pkh(cB[t][2], cB[t][3]));
                *(int2*)&sP[(m0 + ln) * PSTH + 16 + 4 * q] = pv1;
            }
        }

        // ---- prefetch next layer's weights (hidden under the spline) ----
        WFrag wfn;
        if (j + 1 < GDIMS) wfn = load_wfrag(wbuf, ly, ln, q);

        // ---- spline: row tid, sP rows written by OWN wave (lgkm-ordered) ----
        {
            const _Float16* pp = &sP[tid * PSTH];
            float pr[24];
#pragma unroll
            for (int u = 0; u < 6; ++u) {
                half4v hv = *(const half4v*)(pp + 4 * u);
                pr[4*u+0] = (float)hv[0];
                pr[4*u+1] = (float)hv[1];
                pr[4*u+2] = (float)hv[2];
                pr[4*u+3] = (float)hv[3];
            }
            float ld;
            zreg[j] = rqs_apply(xarr[j], pr, ld);
            ldacc += ld;
        }
        if (j + 1 < GDIMS) wf = wfn;
    }

    float4 zv = make_float4(zreg[0], zreg[1], zreg[2], zreg[3]);
    *(float4*)(zo + row * DD + ly0) = zv;
    unsafeAtomicAdd(&ldo[row], ldacc);
}

extern "C" void kernel_launch(void* const* d_in, const int* in_sizes, int n_in,
                              void* d_out, int out_size, void* d_ws, size_t ws_size,
                              hipStream_t stream) {
    const float* x  = (const float*)d_in[0];
    const float* p0 = (const float*)d_in[1];
    const float* w1 = (const float*)d_in[2];
    const float* b1 = (const float*)d_in[3];
    const float* w2 = (const float*)d_in[4];
    const float* b2 = (const float*)d_in[5];
    const float* w3 = (const float*)d_in[6];
    const float* b3 = (const float*)d_in[7];

    const int B = in_sizes[0] / DD;            // 65536
    float* zo  = (float*)d_out;
    float* ldo = zo + (size_t)B * DD;
    char* wbuf = (char*)d_ws;                  // 31 * 8192 B = 254 KB

    hipLaunchKernelGGL(k_prep, dim3(95), dim3(256), 0, stream,
                       w1, b1, w2, b2, w3, b3, wbuf, ldo, B);
    hipLaunchKernelGGL(k_nsf, dim3(B / ROWS, DD / GDIMS), dim3(TPB), 0, stream,
                       x, p0, wbuf, zo, ldo, B);
}